// Round 12
// baseline (57.759 us; speedup 1.0000x reference)
//
#include <hip/hip_runtime.h>

#define BB 4
#define NN 8192
#define THREADS 256
#define CPB 2048               // cols per block (quarter of N)
#define CC 512                 // cols staged per chunk
#define NCHUNK (CPB / CC)      // 4
#define TPC (CC / 32)          // 16 tiles per chunk per wave

typedef float f32x16 __attribute__((ext_vector_type(16)));
typedef __bf16 bf16x8 __attribute__((ext_vector_type(8)));

// ws layout:
//   [0, 128K)   : min1[32768] (uint bits of d^2)
//   [128K,256K) : min2[32768]
//   [256K, ...) : 8 vec planes of 32768 uint4 (512KB each):
//                 (role r: 0=gtA, 1=predA, 2=gtB, 3=predB) x (half h: 0,1)
//                 plane(r,h) at VOFF + (r*2+h)*512KB
#define VOFF (1u << 18)

__device__ inline unsigned short brne(float x) {   // fp32 -> bf16 RNE bits
    unsigned u = __float_as_uint(x);
    return (unsigned short)((u + 0x7FFFu + ((u >> 16) & 1)) >> 16);
}
__device__ inline unsigned pk(unsigned a, unsigned b) { return a | (b << 16); }

__device__ inline const uint4* vplane(const unsigned* ws, int r, int h) {
    return (const uint4*)((const char*)ws + VOFF + (((unsigned)(r * 2 + h)) << 19));
}

// 131072 threads: tid = role(4) x batch(4) x n(8192). Also inits mins.
__global__ __launch_bounds__(256) void cd_pre_kernel(
    const float* __restrict__ pred, const float* __restrict__ gt,
    const float* __restrict__ coords, unsigned int* __restrict__ ws)
{
    int tid = blockIdx.x * 256 + threadIdx.x;
    if (tid < 65536) ws[tid] = 0x7F800000u;   // min1/min2 = +inf

    int r = tid >> 15;            // 0 gtA, 1 predA, 2 gtB, 3 predB
    int b = (tid >> 13) & 3;
    int n = tid & 8191;
    const float* sb = ((r & 1) ? pred : gt) + b * 3 * NN;
    const float* cb = coords + b * 3 * NN;
    float x = cb[0 * NN + n] + sb[0 * NN + n];
    float y = cb[1 * NN + n] + sb[1 * NN + n];
    float z = cb[2 * NN + n] + sb[2 * NN + n];
    float w = -0.5f * fmaf(x, x, fmaf(y, y, z * z));

    unsigned short hx = brne(x); unsigned short lx = brne(x - __uint_as_float((unsigned)hx << 16));
    unsigned short hy = brne(y); unsigned short ly = brne(y - __uint_as_float((unsigned)hy << 16));
    unsigned short hz = brne(z); unsigned short lz = brne(z - __uint_as_float((unsigned)hz << 16));
    unsigned short hw = brne(w); unsigned short lw = brne(w - __uint_as_float((unsigned)hw << 16));
    const unsigned short ONE = 0x3F80;

    uint4 h0, h1;
    if (r < 2) {       // A slots: hx hy hz lx ly lz hx hy | hz hw lw 1 1 0 0 0
        h0 = make_uint4(pk(hx, hy), pk(hz, lx), pk(ly, lz), pk(hx, hy));
        h1 = make_uint4(pk(hz, hw), pk(lw, ONE), pk(ONE, 0), 0u);
    } else {           // B slots: hx hy hz hx hy hz lx ly | lz 1 1 hw lw 0 0 0
        h0 = make_uint4(pk(hx, hy), pk(hz, hx), pk(hy, hz), pk(lx, ly));
        h1 = make_uint4(pk(lz, ONE), pk(ONE, hw), pk(lw, 0), 0u);
    }
    unsigned idx = (unsigned)(b * 8192 + n);
    ((uint4*)((char*)ws + VOFF + (((unsigned)(r * 2 + 0)) << 19)))[idx] = h0;
    ((uint4*)((char*)ws + VOFF + (((unsigned)(r * 2 + 1)) << 19)))[idx] = h1;
}

// grid 2048: (cq 4) x (pb 64) x (b 4) x (dir 2); block = 4 waves, 128 rows, 2048 cols
__global__ __launch_bounds__(THREADS) void cd_mfma_kernel(unsigned int* ws)
{
    __shared__ uint4 colv[2 * CC];   // [0,CC): half0, [CC,2CC): half1  (16 KB)

    int bid = blockIdx.x;
    int cq  = bid & 3;
    int pb  = (bid >> 2) & 63;
    int b   = (bid >> 8) & 3;
    int dir = bid >> 10;

    int tid  = threadIdx.x;
    int w    = tid >> 6;
    int lane = tid & 63;
    int cl   = lane & 31;
    int hi   = lane >> 5;

    // dir0: rows=gt(A) vs cols=pred(B) -> min1 ; dir1: rows=pred(A) vs cols=gt(B) -> min2
    const uint4* Ah = vplane(ws, dir ? 1 : 0, hi);
    const uint4* B0 = vplane(ws, dir ? 2 : 3, 0);
    const uint4* B1 = vplane(ws, dir ? 2 : 3, 1);

    int arow = b * 8192 + pb * 128 + w * 32 + cl;
    bf16x8 afrag = __builtin_bit_cast(bf16x8, Ah[arow]);

    f32x16 zacc{};
    float rm[16];
#pragma unroll
    for (int j = 0; j < 16; j++) rm[j] = -3.0e38f;

    int colbase = b * 8192 + cq * CPB;

    for (int ck = 0; ck < NCHUNK; ++ck) {
        __syncthreads();                       // prior chunk consumed
        int s = colbase + ck * CC + tid;
        uint4 v0 = B0[s], v1 = B0[s + 256];
        uint4 v2 = B1[s], v3 = B1[s + 256];
        colv[tid]            = v0;
        colv[tid + 256]      = v1;
        colv[CC + tid]       = v2;
        colv[CC + tid + 256] = v3;
        __syncthreads();

        const uint4* lbase = &colv[hi * CC + cl];
#pragma unroll
        for (int t = 0; t < TPC; t++) {
            bf16x8 bf = __builtin_bit_cast(bf16x8, lbase[t * 32]);
            f32x16 d = __builtin_amdgcn_mfma_f32_32x32x16_bf16(afrag, bf, zacc, 0, 0, 0);
#pragma unroll
            for (int j = 0; j < 16; j++) rm[j] = fmaxf(rm[j], d[j]);
        }
    }

    // fold rm across the 32 col-lanes (row identity depends only on (w,hi,j))
#pragma unroll
    for (int j = 0; j < 16; j++) {
        float v = rm[j];
        v = fmaxf(v, __shfl_xor(v, 1, 64));
        v = fmaxf(v, __shfl_xor(v, 2, 64));
        v = fmaxf(v, __shfl_xor(v, 4, 64));
        v = fmaxf(v, __shfl_xor(v, 8, 64));
        v = fmaxf(v, __shfl_xor(v, 16, 64));
        rm[j] = v;
    }
    if (cl == 0) {
        unsigned int* minout = ws + (dir ? 32768 : 0);
#pragma unroll
        for (int j = 0; j < 16; j++) {
            int row = pb * 128 + w * 32 + (j & 3) + 8 * (j >> 2) + 4 * hi;
            float d2 = fmaxf(-2.0f * rm[j], 0.0f);
            atomicMin(&minout[b * 8192 + row], __float_as_uint(d2));
        }
    }
}

__global__ __launch_bounds__(1024) void cd_reduce_kernel(const unsigned int* __restrict__ mins,
                                                         float* __restrict__ out)
{
    float s = 0.0f;
#pragma unroll
    for (int k = 0; k < 2 * BB * NN / 1024; ++k)
        s += __uint_as_float(mins[threadIdx.x + k * 1024]);
#pragma unroll
    for (int off = 32; off > 0; off >>= 1)
        s += __shfl_down(s, off, 64);
    __shared__ float wsum[16];
    int wave = threadIdx.x >> 6;
    if ((threadIdx.x & 63) == 0) wsum[wave] = s;
    __syncthreads();
    if (threadIdx.x == 0) {
        float t = 0.0f;
#pragma unroll
        for (int v = 0; v < 16; ++v) t += wsum[v];
        out[0] = t / (float)BB;
    }
}

extern "C" void kernel_launch(void* const* d_in, const int* in_sizes, int n_in,
                              void* d_out, int out_size, void* d_ws, size_t ws_size,
                              hipStream_t stream) {
    const float* pred   = (const float*)d_in[0];
    const float* gt     = (const float*)d_in[1];
    const float* coords = (const float*)d_in[2];
    float* out = (float*)d_out;
    unsigned int* ws = (unsigned int*)d_ws;

    hipLaunchKernelGGL(cd_pre_kernel, dim3(512), dim3(256), 0, stream,
                       pred, gt, coords, ws);
    hipLaunchKernelGGL(cd_mfma_kernel, dim3(2048), dim3(256), 0, stream, ws);
    hipLaunchKernelGGL(cd_reduce_kernel, dim3(1), dim3(1024), 0, stream, ws, out);
}